// Round 9
// baseline (404.158 us; speedup 1.0000x reference)
//
#include <hip/hip_runtime.h>

typedef unsigned short u16;
typedef unsigned int u32;
typedef short s8v __attribute__((ext_vector_type(8)));    // 8 x bf16 bits (4 VGPRs)
typedef float f16v __attribute__((ext_vector_type(16)));  // 32x32 MFMA accumulator
typedef u32 u32x4 __attribute__((ext_vector_type(4)));

// ---------- helpers ----------
__device__ __forceinline__ u16 f2bf(float f) {
    u32 u = __float_as_uint(f);
    u += 0x7FFFu + ((u >> 16) & 1u);   // round-to-nearest-even
    return (u16)(u >> 16);
}

// ---------- kernel 0: style (once per b, coalesced mod_w via LDS) ----------
__global__ void style_kernel(const float* __restrict__ norm_feat,  // [8][64]
                             const float* __restrict__ mod_w,      // [256][64]
                             const float* __restrict__ mod_b,      // [256]
                             float* __restrict__ style) {          // [8][256]
    __shared__ float nf[64];
    __shared__ float mw[256][65];
    const int b = blockIdx.x;
    const int tid = threadIdx.x;

    if (tid < 64) nf[tid] = norm_feat[b * 64 + tid];
    #pragma unroll
    for (int i = 0; i < 64; ++i) {
        int idx = i * 256 + tid;
        mw[idx >> 6][idx & 63] = mod_w[idx];
    }
    __syncthreads();

    float s = mod_b[tid];
    #pragma unroll 8
    for (int d = 0; d < 64; ++d) s += nf[d] * mw[tid][d];
    style[b * 256 + tid] = s;
}

// ---------- kernel 1: demod + modulated bf16 weights ----------
// grid (256 co, 8 b), 256 threads (thread = ci)
// Wmod layout for 32x32x16 fragments:
//   [b][t][cob=co>>5 (8)][cib=ci>>4 (16)][lane=(co&31)+32*((ci>>3)&1)][elem=ci&7]
// weight[co] slice staged in LDS via coalesced loads.
__global__ void modulate_kernel(const float* __restrict__ style,   // [8][256]
                                const float* __restrict__ weight,  // [256][256][9]
                                u16* __restrict__ Wmod) {
    const int co = blockIdx.x;
    const int b  = blockIdx.y;
    const int ci = threadIdx.x;

    __shared__ float wlds[2304];
    __shared__ float red[256];

    const float* wsrc = weight + (size_t)co * 2304;
    #pragma unroll
    for (int i = 0; i < 9; ++i) wlds[i * 256 + ci] = wsrc[i * 256 + ci];

    const float s = style[b * 256 + ci];
    __syncthreads();

    // per-thread 9 taps from LDS: addr stride 9, gcd(9,32)=1 -> conflict-free
    float w9[9];
    float sq = 0.f;
    #pragma unroll
    for (int t = 0; t < 9; ++t) { w9[t] = wlds[ci * 9 + t]; sq += w9[t] * w9[t]; }

    red[ci] = sq * s * s;
    __syncthreads();
    for (int off = 128; off > 0; off >>= 1) {
        if (ci < off) red[ci] += red[ci + off];
        __syncthreads();
    }
    const float scale = 1.0f / 48.0f;              // 1/sqrt(256*9)
    const float demod = rsqrtf(scale * scale * red[0] + 1e-8f);
    const float coef  = scale * s * demod;

    // t=0 base; per-t stride = 8*16*64*8 = 65536 u16
    const size_t tile = (((size_t)b * 9 * 8 + (co >> 5)) * 16 + (ci >> 4)) * 512
                      + (size_t)((co & 31) + 32 * ((ci >> 3) & 1)) * 8 + (ci & 7);
    #pragma unroll
    for (int t = 0; t < 9; ++t) {
        Wmod[tile + (size_t)t * 65536] = f2bf(w9[t] * coef);
    }
}

// ---------- kernel 2: NCHW fp32 -> blocked-NHWC bf16 (R7 LDS version) ----------
// feaT layout: [b][y][ch(16)][cg(2)][x(128)][cil(8)] bf16   (c = ch*16 + cg*8 + cil)
// grid (128 y, 4 cblk, 8 b), 256 threads — one 64-c group per block
__global__ __launch_bounds__(256) void transpose_kernel(const float* __restrict__ fea,
                                                        u16* __restrict__ feaT) {
    __shared__ float lds_t[64][132];   // row = 528B -> float4-aligned, 2-way banks
    const int y  = blockIdx.x;
    const int c0 = blockIdx.y * 64;
    const int b  = blockIdx.z;
    const int tid = threadIdx.x;

    #pragma unroll
    for (int r = 0; r < 8; ++r) {
        int i  = r * 256 + tid;       // 0..2047
        int c  = i >> 5;              // 0..63
        int x4 = i & 31;              // float4 index
        float4 v = *(const float4*)&fea[(((size_t)(b * 256 + c0 + c)) * 128 + y) * 128 + x4 * 4];
        *(float4*)&lds_t[c][x4 * 4] = v;
    }
    __syncthreads();
    #pragma unroll
    for (int jj = 0; jj < 4; ++jj) {
        int p   = jj * 256 + tid;     // 0..1023
        int x   = p & 127;
        int g   = p >> 7;             // 0..7 (granule of 8 c)
        int cb8 = g * 8;
        u32x4 wv;
        #pragma unroll
        for (int k = 0; k < 4; ++k) {
            float f0 = lds_t[cb8 + 2 * k][x];
            float f1 = lds_t[cb8 + 2 * k + 1][x];
            wv[k] = (u32)f2bf(f0) | ((u32)f2bf(f1) << 16);
        }
        int c  = c0 + cb8;
        int ch = c >> 4;
        int cg = (c >> 3) & 1;
        size_t off = (((((size_t)b * 128 + y) * 16 + ch) * 2 + cg) * 128 + x) * 8;
        *(u32x4*)&feaT[off] = wv;
    }
}

// ---------- kernel 3: MFMA conv (shift-GEMM), 32x32x16, NO LDS / NO BARRIERS ----
// grid (128 y, 8 b), 256 threads = 4 waves, each wave = one 64-co block x 128 px.
// B fragments read DIRECTLY from global (feaT blocked layout -> 2x512B coalesced
// per fragment); per-chunk B window = 12KB/block -> vector-L1 resident, ~12x
// reuse served by L1. No __shared__, no __syncthreads, waves free-run.
// acc = 2x4x16 = 128 regs -> 2 waves/SIMD co-resident for mutual latency hiding.
__global__ __launch_bounds__(256, 2) void conv_mfma(
        const u16* __restrict__ Wmod,   // fragment-ordered, see modulate_kernel
        const u16* __restrict__ feaT,   // [8][128][16][2][128][8] bf16
        float* __restrict__ out) {      // [8][256][128][128]
    // XCD swizzle: 1024 wgs = 8 XCDs x 128; each XCD owns one batch b
    // -> its 1.18 MiB Wmod slice stays L2-resident.
    const int lin = blockIdx.x + 128 * blockIdx.y;
    const int nid = (lin & 7) * 128 + (lin >> 3);
    const int y   = nid & 127;
    const int b   = nid >> 7;

    const int tid  = threadIdx.x;
    const int lane = tid & 63;
    const int wave = tid >> 6;          // 0..3 = co block of 64
    const int l31  = lane & 31;
    const int l5   = lane >> 5;         // k-group (8 ci)

    const bool rokU[3] = { y > 0, true, y < 127 };
    const bool xz0  = (l31 == 0);       // x_in = -1  -> zero fragment lane
    const bool xz31 = (l31 == 31);      // x_in = 128 -> zero fragment lane

    // ---- B-side global base pointers, one per kh (advanced 2048 u16/chunk) ----
    // addr(kh; ch, kw, j) = Bb[kh] + ch*2048 + (j*32 + kw)*8
    // gy clamped for address safety only: data at clamped rows is discarded
    // because the kh MFMA block is skipped (rokU) at y edges.
    const u16* Bb[3];
    #pragma unroll
    for (int kh = 0; kh < 3; ++kh) {
        int gy = y - 1 + kh;
        int gyc = gy < 0 ? 0 : (gy > 127 ? 127 : gy);
        Bb[kh] = feaT + ((((size_t)(b * 128 + gyc) * 16) * 2 + l5) * 128 + (l31 - 1)) * 8;
    }

    // A-side: cob = wave*2 + i (i=0..1); strides (u16): t=65536, cob=8192, cib=512
    const u16* Abase = Wmod + (size_t)b * 9 * 65536
                            + (size_t)(wave * 2) * 8192 + (size_t)lane * 8;

    auto loadA = [&](int t, int i, int ch) -> s8v {
        return *(const s8v*)(Abase + (size_t)t * 65536 + (size_t)i * 8192 + (size_t)ch * 512);
    };

    f16v acc[2][4];
    #pragma unroll
    for (int i = 0; i < 2; ++i)
        #pragma unroll
        for (int j = 0; j < 4; ++j) acc[i][j] = (f16v)0.0f;

    // A-fragment ring: distance-3 prefetch, 9 taps % 3 == 0 -> static ring index
    s8v fr[3][2];
    #pragma unroll
    for (int g = 0; g < 3; ++g)
        #pragma unroll
        for (int i = 0; i < 2; ++i) fr[g][i] = loadA(g, i, 0);

    #pragma unroll 1
    for (int ch = 0; ch < 16; ++ch) {
        // B read: kh,kw,j compile-time under full unroll; boundary lanes zeroed
        auto readB = [&](int kh, int kw, int j) -> s8v {
            s8v v = *(const s8v*)(Bb[kh] + (j * 32 + kw) * 8);
            if (kw == 0 && j == 0) { if (xz0)  v = (s8v)0; }
            if (kw == 2 && j == 3) { if (xz31) v = (s8v)0; }
            return v;
        };

        // B double-buffer: tap t+1's reads issued during tap t's MFMAs.
        s8v bfrE[4], bfrO[4];
        #pragma unroll
        for (int j = 0; j < 4; ++j) bfrE[j] = readB(0, 0, j);   // tap 0

        #pragma unroll
        for (int t = 0; t < 9; ++t) {
            const int kh = t / 3;
            const int khn = (t + 1) / 3, kwn = (t + 1) % 3;

            if ((t & 1) == 0) {
                if (t < 8) {
                    #pragma unroll
                    for (int j = 0; j < 4; ++j) bfrO[j] = readB(khn, kwn, j);
                }
                if (rokU[kh]) {
                    #pragma unroll
                    for (int i = 0; i < 2; ++i)
                        #pragma unroll
                        for (int j = 0; j < 4; ++j)
                            acc[i][j] = __builtin_amdgcn_mfma_f32_32x32x16_bf16(
                                fr[t % 3][i], bfrE[j], acc[i][j], 0, 0, 0);
                }
            } else {
                #pragma unroll
                for (int j = 0; j < 4; ++j) bfrE[j] = readB(khn, kwn, j);
                if (rokU[kh]) {
                    #pragma unroll
                    for (int i = 0; i < 2; ++i)
                        #pragma unroll
                        for (int j = 0; j < 4; ++j)
                            acc[i][j] = __builtin_amdgcn_mfma_f32_32x32x16_bf16(
                                fr[t % 3][i], bfrO[j], acc[i][j], 0, 0, 0);
                }
            }

            // A-ring refill: slot t%3 <- fragment needed 3 taps ahead
            // (after the MFMA block: it overwrites fr[t%3]).
            if (t < 6) {
                #pragma unroll
                for (int i = 0; i < 2; ++i) fr[t % 3][i] = loadA(t + 3, i, ch);
            } else if (ch < 15) {
                #pragma unroll
                for (int i = 0; i < 2; ++i) fr[t % 3][i] = loadA(t - 6, i, ch + 1);
            }
        }

        // advance B pointers to next ci chunk (2048 u16 = one ch step)
        Bb[0] += 2048; Bb[1] += 2048; Bb[2] += 2048;
    }

    // epilogue: C/D layout col(n=pixel)=lane&31, row(m=co)=(reg&3)+8*(reg>>2)+4*(lane>>5)
    #pragma unroll
    for (int i = 0; i < 2; ++i) {
        #pragma unroll
        for (int j = 0; j < 4; ++j) {
            #pragma unroll
            for (int reg = 0; reg < 16; ++reg) {
                int co = wave * 64 + i * 32 + (reg & 3) + 8 * (reg >> 2) + 4 * l5;
                int x  = j * 32 + l31;
                out[(((size_t)(b * 256 + co) * 128 + y) * 128) + x] = acc[i][j][reg];
            }
        }
    }
}

// ---------- launch ----------
extern "C" void kernel_launch(void* const* d_in, const int* in_sizes, int n_in,
                              void* d_out, int out_size, void* d_ws, size_t ws_size,
                              hipStream_t stream) {
    const float* fea       = (const float*)d_in[0];
    const float* norm_feat = (const float*)d_in[1];
    const float* mod_w     = (const float*)d_in[2];
    const float* mod_b     = (const float*)d_in[3];
    const float* weight    = (const float*)d_in[4];
    float* out = (float*)d_out;

    // workspace: Wmod bf16 = 9 MiB, then feaT bf16 = 64 MiB.
    // style (8 KiB fp32) lives at the head of the feaT region (serialized reuse).
    u16* Wmod = (u16*)d_ws;
    u16* feaT = (u16*)((char*)d_ws + 9u * 1024u * 1024u);
    float* style = (float*)feaT;

    style_kernel<<<dim3(8), 256, 0, stream>>>(norm_feat, mod_w, mod_b, style);
    modulate_kernel<<<dim3(256, 8), 256, 0, stream>>>(style, weight, Wmod);
    transpose_kernel<<<dim3(128, 4, 8), 256, 0, stream>>>(fea, feaT);
    conv_mfma<<<dim3(128, 8), 256, 0, stream>>>(Wmod, feaT, out);
}

// Round 10
// 369.146 us; speedup vs baseline: 1.0948x; 1.0948x over previous
//
#include <hip/hip_runtime.h>

typedef unsigned short u16;
typedef unsigned int u32;
typedef short s8v __attribute__((ext_vector_type(8)));    // 8 x bf16 bits (4 VGPRs)
typedef float f16v __attribute__((ext_vector_type(16)));  // 32x32 MFMA accumulator
typedef u32 u32x4 __attribute__((ext_vector_type(4)));

// ---------- helpers ----------
__device__ __forceinline__ u16 f2bf(float f) {
    u32 u = __float_as_uint(f);
    u += 0x7FFFu + ((u >> 16) & 1u);   // round-to-nearest-even
    return (u16)(u >> 16);
}

__device__ __forceinline__ void async_load16(const u16* g, u16* l) {
    // global -> LDS DMA, 16B per lane; LDS dest = wave-uniform base + lane*16
    __builtin_amdgcn_global_load_lds(
        (const __attribute__((address_space(1))) u32*)g,
        (__attribute__((address_space(3))) u32*)l,
        16, 0, 0);
}

// ---------- kernel 0: style (once per b, coalesced mod_w via LDS) ----------
__global__ void style_kernel(const float* __restrict__ norm_feat,  // [8][64]
                             const float* __restrict__ mod_w,      // [256][64]
                             const float* __restrict__ mod_b,      // [256]
                             float* __restrict__ style) {          // [8][256]
    __shared__ float nf[64];
    __shared__ float mw[256][65];
    const int b = blockIdx.x;
    const int tid = threadIdx.x;

    if (tid < 64) nf[tid] = norm_feat[b * 64 + tid];
    #pragma unroll
    for (int i = 0; i < 64; ++i) {
        int idx = i * 256 + tid;
        mw[idx >> 6][idx & 63] = mod_w[idx];
    }
    __syncthreads();

    float s = mod_b[tid];
    #pragma unroll 8
    for (int d = 0; d < 64; ++d) s += nf[d] * mw[tid][d];
    style[b * 256 + tid] = s;
}

// ---------- kernel 1: demod + modulated bf16 weights ----------
// grid (256 co, 8 b), 256 threads (thread = ci)
// Wmod layout for 32x32x16 fragments:
//   [b][t][cob=co>>5 (8)][cib=ci>>4 (16)][lane=(co&31)+32*((ci>>3)&1)][elem=ci&7]
// weight[co] slice staged in LDS via coalesced loads.
__global__ void modulate_kernel(const float* __restrict__ style,   // [8][256]
                                const float* __restrict__ weight,  // [256][256][9]
                                u16* __restrict__ Wmod) {
    const int co = blockIdx.x;
    const int b  = blockIdx.y;
    const int ci = threadIdx.x;

    __shared__ float wlds[2304];
    __shared__ float red[256];

    const float* wsrc = weight + (size_t)co * 2304;
    #pragma unroll
    for (int i = 0; i < 9; ++i) wlds[i * 256 + ci] = wsrc[i * 256 + ci];

    const float s = style[b * 256 + ci];
    __syncthreads();

    // per-thread 9 taps from LDS: addr stride 9, gcd(9,32)=1 -> conflict-free
    float w9[9];
    float sq = 0.f;
    #pragma unroll
    for (int t = 0; t < 9; ++t) { w9[t] = wlds[ci * 9 + t]; sq += w9[t] * w9[t]; }

    red[ci] = sq * s * s;
    __syncthreads();
    for (int off = 128; off > 0; off >>= 1) {
        if (ci < off) red[ci] += red[ci + off];
        __syncthreads();
    }
    const float scale = 1.0f / 48.0f;              // 1/sqrt(256*9)
    const float demod = rsqrtf(scale * scale * red[0] + 1e-8f);
    const float coef  = scale * s * demod;

    // t=0 base; per-t stride = 8*16*64*8 = 65536 u16
    const size_t tile = (((size_t)b * 9 * 8 + (co >> 5)) * 16 + (ci >> 4)) * 512
                      + (size_t)((co & 31) + 32 * ((ci >> 3) & 1)) * 8 + (ci & 7);
    #pragma unroll
    for (int t = 0; t < 9; ++t) {
        Wmod[tile + (size_t)t * 65536] = f2bf(w9[t] * coef);
    }
}

// ---------- kernel 2: NCHW fp32 -> blocked-NHWC bf16 (R7 LDS version) ----------
// feaT layout: [b][y][ch(16)][cg(2)][x(128)][cil(8)] bf16   (c = ch*16 + cg*8 + cil)
// grid (128 y, 4 cblk, 8 b), 256 threads — one 64-c group per block
__global__ __launch_bounds__(256) void transpose_kernel(const float* __restrict__ fea,
                                                        u16* __restrict__ feaT) {
    __shared__ float lds_t[64][132];   // row = 528B -> float4-aligned, 2-way banks
    const int y  = blockIdx.x;
    const int c0 = blockIdx.y * 64;
    const int b  = blockIdx.z;
    const int tid = threadIdx.x;

    #pragma unroll
    for (int r = 0; r < 8; ++r) {
        int i  = r * 256 + tid;       // 0..2047
        int c  = i >> 5;              // 0..63
        int x4 = i & 31;              // float4 index
        float4 v = *(const float4*)&fea[(((size_t)(b * 256 + c0 + c)) * 128 + y) * 128 + x4 * 4];
        *(float4*)&lds_t[c][x4 * 4] = v;
    }
    __syncthreads();
    #pragma unroll
    for (int jj = 0; jj < 4; ++jj) {
        int p   = jj * 256 + tid;     // 0..1023
        int x   = p & 127;
        int g   = p >> 7;             // 0..7 (granule of 8 c)
        int cb8 = g * 8;
        u32x4 wv;
        #pragma unroll
        for (int k = 0; k < 4; ++k) {
            float f0 = lds_t[cb8 + 2 * k][x];
            float f1 = lds_t[cb8 + 2 * k + 1][x];
            wv[k] = (u32)f2bf(f0) | ((u32)f2bf(f1) << 16);
        }
        int c  = c0 + cb8;
        int ch = c >> 4;
        int cg = (c >> 3) & 1;
        size_t off = (((((size_t)b * 128 + y) * 16 + ch) * 2 + cg) * 128 + x) * 8;
        *(u32x4*)&feaT[off] = wv;
    }
}

// ---------- kernel 3: MFMA conv (shift-GEMM), 32x32x16, 128co x 128px wave tile --
// grid (64 y-pairs, 8 b), 256 threads = 4 waves (mw2 x yw2), 2 output rows/block
// R8 structure (best measured: 143.5 us, MfmaUtil 48) + CHUNK PHASE STAGGER:
// co-resident blocks (y and y+32 share a CU) start the ci-loop 8 chunks apart,
// de-synchronizing the XCD-wide phase-locked A-refill bursts to L2 and the
// barrier stalls. Rotated chunk order sums the same 16 partials.
__global__ __launch_bounds__(256, 1) void conv_mfma(
        const u16* __restrict__ Wmod,   // fragment-ordered, see modulate_kernel
        const u16* __restrict__ feaT,   // [8][128][16][2][128][8] bf16
        float* __restrict__ out) {      // [8][256][128][128]
    // per-parity: 8192 u16 fea ([row4][cg2][x128][8ci]) + 16 u16 zero pad
    __shared__ u16 lds[2][8208];        // 32,832 B

    // XCD swizzle: 512 wgs = 8 XCDs x 64; each XCD owns one batch b
    const int lin = blockIdx.x + 64 * blockIdx.y;
    const int nid = (lin & 7) * 64 + (lin >> 3);
    const int yp  = nid & 63;           // y-pair: rows 2*yp, 2*yp+1
    const int b   = nid >> 6;

    // chunk phase: blocks that co-reside on a CU (yp and yp+32) start 8 apart
    const int phase = ((yp >> 5) & 1) * 8;

    const int tid  = threadIdx.x;
    const int lane = tid & 63;
    const int wave = tid >> 6;          // 0..3
    const int mw   = wave & 1;          // co half (128 of 256)
    const int ywv  = wave >> 1;         // output row within pair (vector)
    const int l31  = lane & 31;
    const int l5   = lane >> 5;         // k-group (8 ci)

    // wave-uniform scalar copies (drive scalar branches for y-edge taps)
    const int yw_s   = __builtin_amdgcn_readfirstlane(ywv);
    const int y_out_s = 2 * yp + yw_s;
    const bool rokU[3] = { y_out_s > 0, true, y_out_s < 127 };

    // zero both parity pads (16 u16 each)
    if (tid < 16) { lds[0][8192 + tid] = 0; lds[1][8192 + tid] = 0; }

    // ---- B-side LDS offsets (u16 units, rel. to parity base) ----
    int rb[3], bqL[3], bqR[3];
    #pragma unroll
    for (int kh = 0; kh < 3; ++kh) {
        const int rr = ywv + kh;                      // LDS row 0..3
        const int o  = ((rr * 2 + l5) * 128 + (l31 - 1)) * 8;
        rb[kh]  = o;
        bqL[kh] = (l31 > 0)  ? o : 8192;              // x_in = -1 -> zero pad
        bqR[kh] = (l31 < 31) ? (o + 3 * 256 + 16) : 8192;  // x_in = 128 -> pad
    }

    // A-side: cob = mw*4 + i (i=0..3); strides (u16): t=65536, cob=8192, cib=512
    const u16* Abase = Wmod + (size_t)b * 9 * 65536
                            + (size_t)(mw * 4) * 8192 + (size_t)lane * 8;

    auto loadA = [&](int t, int i, int ch) -> s8v {
        return *(const s8v*)(Abase + (size_t)t * 65536 + (size_t)i * 8192 + (size_t)ch * 512);
    };

    // stage one 16-ci chunk: 16 contiguous 1024B DMA units; wave w covers
    // (cg,xq) = (w>>1, w&1), rows r=0..3.
    auto stage = [&](int buf, int ch) {
        u16* ldsb = &lds[buf][0];
        const int cg = wave >> 1;
        const int xq = wave & 1;
        #pragma unroll
        for (int r = 0; r < 4; ++r) {
            int gy = 2 * yp - 1 + r;
            if ((unsigned)gy < 128u) {
                const u16* g = feaT +
                    (((((size_t)b * 128 + gy) * 16 + ch) * 2 + cg) * 128 + xq * 64) * 8
                    + (size_t)lane * 8;
                async_load16(g, ldsb + ((r * 2 + cg) * 128 + xq * 64) * 8);
            }
        }
    };

    f16v acc[4][4];
    #pragma unroll
    for (int i = 0; i < 4; ++i)
        #pragma unroll
        for (int j = 0; j < 4; ++j) acc[i][j] = (f16v)0.0f;

    // A-fragment ring: distance-3 prefetch, 9 taps % 3 == 0 -> static ring index
    s8v fr[3][4];

    // prologue: stage first chunk (= phase), preload its taps 0..2
    stage(0, phase);
    #pragma unroll
    for (int g = 0; g < 3; ++g)
        #pragma unroll
        for (int i = 0; i < 4; ++i) fr[g][i] = loadA(g, i, phase);
    __syncthreads();

    #pragma unroll 1
    for (int chi = 0; chi < 16; ++chi) {
        const int ch  = (chi + phase) & 15;          // rotated chunk order
        const int chn = (ch + 1) & 15;               // next chunk (if any)
        const u16* basep = &lds[chi & 1][0];

        // B read helper: kh,kw,j compile-time under full unroll
        auto readB = [&](int kh, int kw, int j) -> s8v {
            const u16* p;
            if (j == 0 && kw == 0)      p = basep + bqL[kh];
            else if (j == 3 && kw == 2) p = basep + bqR[kh];
            else                        p = basep + rb[kh] + (j * 256 + kw * 8);
            return *(const s8v*)p;
        };

        // B double-buffer: tap t+1's reads issued during tap t's MFMAs.
        s8v bfrE[4], bfrO[4];
        #pragma unroll
        for (int j = 0; j < 4; ++j) bfrE[j] = readB(0, 0, j);   // tap 0 fresh

        #pragma unroll
        for (int t = 0; t < 9; ++t) {
            const int kh = t / 3;
            const int khn = (t + 1) / 3, kwn = (t + 1) % 3;

            if ((t & 1) == 0) {
                if (t < 8) {
                    #pragma unroll
                    for (int j = 0; j < 4; ++j) bfrO[j] = readB(khn, kwn, j);
                }
                if (rokU[kh]) {
                    #pragma unroll
                    for (int i = 0; i < 4; ++i)
                        #pragma unroll
                        for (int j = 0; j < 4; ++j)
                            acc[i][j] = __builtin_amdgcn_mfma_f32_32x32x16_bf16(
                                fr[t % 3][i], bfrE[j], acc[i][j], 0, 0, 0);
                }
            } else {
                #pragma unroll
                for (int j = 0; j < 4; ++j) bfrE[j] = readB(khn, kwn, j);
                if (rokU[kh]) {
                    #pragma unroll
                    for (int i = 0; i < 4; ++i)
                        #pragma unroll
                        for (int j = 0; j < 4; ++j)
                            acc[i][j] = __builtin_amdgcn_mfma_f32_32x32x16_bf16(
                                fr[t % 3][i], bfrO[j], acc[i][j], 0, 0, 0);
                }
            }

            // stage next chunk BEFORE the t3 A-refill so the t6 refill-consume
            // wait drains the stage DMAs (keeps the vmcnt(12) proof valid).
            if (t == 3 && chi < 15) {
                __builtin_amdgcn_sched_barrier(0);
                stage((chi + 1) & 1, chn);
                __builtin_amdgcn_sched_barrier(0);
            }

            // A-ring refill: slot t%3 <- fragment needed 3 taps ahead.
            // (must stay AFTER the MFMA block: it overwrites fr[t%3])
            if (t < 6) {
                #pragma unroll
                for (int i = 0; i < 4; ++i) fr[t % 3][i] = loadA(t + 3, i, ch);
            } else if (chi < 15) {
                #pragma unroll
                for (int i = 0; i < 4; ++i) fr[t % 3][i] = loadA(t - 6, i, chn);
            }
        }

        if (chi < 15) {
            // counted-vmcnt barrier (T4): the 12 next-chunk A-refills (taps 6-8)
            // stay in flight; everything older (incl. stage DMAs) completes.
            asm volatile("s_waitcnt vmcnt(12)" ::: "memory");
            __builtin_amdgcn_sched_barrier(0);
            __builtin_amdgcn_s_barrier();
            __builtin_amdgcn_sched_barrier(0);
        }
    }

    // epilogue: C/D layout col(n=pixel)=lane&31, row(m=co)=(reg&3)+8*(reg>>2)+4*(lane>>5)
    const int y_out = 2 * yp + ywv;
    #pragma unroll
    for (int i = 0; i < 4; ++i) {
        #pragma unroll
        for (int j = 0; j < 4; ++j) {
            #pragma unroll
            for (int reg = 0; reg < 16; ++reg) {
                int co = mw * 128 + i * 32 + (reg & 3) + 8 * (reg >> 2) + 4 * l5;
                int x  = j * 32 + l31;
                out[(((size_t)(b * 256 + co) * 128 + y_out) * 128) + x] = acc[i][j][reg];
            }
        }
    }
}

// ---------- launch ----------
extern "C" void kernel_launch(void* const* d_in, const int* in_sizes, int n_in,
                              void* d_out, int out_size, void* d_ws, size_t ws_size,
                              hipStream_t stream) {
    const float* fea       = (const float*)d_in[0];
    const float* norm_feat = (const float*)d_in[1];
    const float* mod_w     = (const float*)d_in[2];
    const float* mod_b     = (const float*)d_in[3];
    const float* weight    = (const float*)d_in[4];
    float* out = (float*)d_out;

    // workspace: Wmod bf16 = 9 MiB, then feaT bf16 = 64 MiB.
    // style (8 KiB fp32) lives at the head of the feaT region (serialized reuse).
    u16* Wmod = (u16*)d_ws;
    u16* feaT = (u16*)((char*)d_ws + 9u * 1024u * 1024u);
    float* style = (float*)feaT;

    style_kernel<<<dim3(8), 256, 0, stream>>>(norm_feat, mod_w, mod_b, style);
    modulate_kernel<<<dim3(256, 8), 256, 0, stream>>>(style, weight, Wmod);
    transpose_kernel<<<dim3(128, 4, 8), 256, 0, stream>>>(fea, feaT);
    conv_mfma<<<dim3(64, 8), 256, 0, stream>>>(Wmod, feaT, out);
}